// Round 4
// baseline (709.236 us; speedup 1.0000x reference)
//
#include <hip/hip_runtime.h>

// ---------------------------------------------------------------------------
// RNNAgent forward: fc1+ReLU -> GRUCell -> two Q heads (interleaved), bf16 MFMA
// B=65536, IN2=256, H2=512, A=32.
// v3 (resubmit; round-3 run was an infra failure): 2-phase double-buffered
// pipeline (stage-early / drain-at-barrier), XCD-aware work swizzle, setprio
// around MFMA, rebuilt fc1/heads, fused cvt.
// ---------------------------------------------------------------------------

#define BATCH 65536
#define IN2   256
#define H2    512
#define NA    32
#define QELEMS (2 * BATCH * NA)

typedef float  f32x4  __attribute__((ext_vector_type(4)));
typedef short  short8 __attribute__((ext_vector_type(8)));
typedef __bf16 bf16x8 __attribute__((ext_vector_type(8)));
typedef unsigned short ushort_t;

__device__ __forceinline__ f32x4 mfma16(short8 a, short8 b, f32x4 c) {
  return __builtin_amdgcn_mfma_f32_16x16x32_bf16(
      __builtin_bit_cast(bf16x8, a), __builtin_bit_cast(bf16x8, b), c, 0, 0, 0);
}

__device__ __forceinline__ unsigned short f2bf(float f) {
  union { float f; unsigned u; } v; v.f = f;
  unsigned r = v.u + 0x7fffu + ((v.u >> 16) & 1u);
  return (unsigned short)(r >> 16);
}
__device__ __forceinline__ float bf2f(unsigned short u) {
  union { unsigned u; float f; } v; v.u = ((unsigned)u) << 16; return v.f;
}

__device__ __forceinline__ void gload16(const void* g, void* l) {
  __builtin_amdgcn_global_load_lds(
      (const __attribute__((address_space(1))) void*)g,
      (__attribute__((address_space(3))) void*)l, 16, 0, 0);
}

__device__ __forceinline__ float sigm(float x) {
  return 1.f / (1.f + __expf(-x));
}
__device__ __forceinline__ float tanh_fast(float x) {
  float t = __expf(-2.f * fabsf(x));
  float r = (1.f - t) / (1.f + t);
  return x >= 0.f ? r : -r;
}

// ---------------------------------------------------------------------------
// fused cvt: hidden + all 5 weight tensors -> bf16, one launch.
// f4 segments: hidden 8388608 | W1 32768 | Wih 196608 | Whh 196608 |
//              W21 4096 | W22 4096  (total 8822784)
// ---------------------------------------------------------------------------
__global__ void cvt_all(const float* __restrict__ hid,
                        const float* __restrict__ W1,
                        const float* __restrict__ Wih,
                        const float* __restrict__ Whh,
                        const float* __restrict__ W21,
                        const float* __restrict__ W22,
                        ushort_t* __restrict__ h16,
                        ushort_t* __restrict__ dW1,
                        ushort_t* __restrict__ dWih,
                        ushort_t* __restrict__ dWhh,
                        ushort_t* __restrict__ dW21,
                        ushort_t* __restrict__ dW22) {
  for (int i = blockIdx.x * blockDim.x + threadIdx.x; i < 8822784;
       i += gridDim.x * blockDim.x) {
    const float* s; ushort_t* d; int lo;
    if (i < 8388608) { s = hid; d = h16; lo = i; }
    else {
      int k = i - 8388608;
      if      (k < 32768)  { s = W1;  d = dW1;  lo = k; }
      else if (k < 229376) { s = Wih; d = dWih; lo = k - 32768; }
      else if (k < 425984) { s = Whh; d = dWhh; lo = k - 229376; }
      else if (k < 430080) { s = W21; d = dW21; lo = k - 425984; }
      else                 { s = W22; d = dW22; lo = k - 430080; }
    }
    float4 f = ((const float4*)s)[lo];
    ushort4 o;
    o.x = f2bf(f.x); o.y = f2bf(f.y); o.z = f2bf(f.z); o.w = f2bf(f.w);
    ((ushort4*)d)[lo] = o;
  }
}

// ---------------------------------------------------------------------------
// fc1: x = relu(in @ W1^T + b1).  inputs fp32 [B][256], W bf16 [512][256].
// Tile 128x64, 4 waves 2x2 (64r x 32c), BK=32, double-buffered 2-phase.
// A reg-staged (load early, cvt+ds_write late); W via global_load_lds.
// LDS/buf = A 8K + W 4K = 12K; x2 = 24 KB.
// ---------------------------------------------------------------------------
__global__ __launch_bounds__(256, 4)
void fc1_kernel(const float* __restrict__ A,
                const ushort_t* __restrict__ W,
                const float* __restrict__ bias,
                ushort_t* __restrict__ X) {
  __shared__ char ldsb[24576];
  const int tid  = threadIdx.x;
  const int lane = tid & 63, wid = tid >> 6;
  const int l16  = lane & 15;
  const int bid  = blockIdx.x;
  const int lin  = (bid & 7) * 512 + (bid >> 3);     // XCD-local work order
  const int row0 = (lin >> 3) * 128;
  const int col0 = (lin & 7) * 64;
  const int wrow = (wid >> 1) * 64;
  const int wcol = (wid & 1) * 32;
  const int lr   = lane >> 2;
  const int sc8  = ((lane & 3) ^ (lr & 3)) * 8;      // pre-swizzled src col
  const int rdx  = (((lane >> 4) ^ (lane & 3)) << 4);

  f32x4 acc[4][2] = {};
  float4 ra[2], rb[2];
  char* buf0 = ldsb;
  char* buf1 = ldsb + 12288;

  auto LOADA = [&](int t) {
#pragma unroll
    for (int i = 0; i < 2; ++i) {
      const float* p =
          A + (size_t)(row0 + (wid * 2 + i) * 16 + lr) * IN2 + t * 32 + sc8;
      ra[i] = *(const float4*)p;
      rb[i] = *(const float4*)(p + 4);
    }
  };
  auto GW = [&](int t, char* buf) {
    const int jrow = col0 + wid * 16 + lr;
    gload16(W + (size_t)jrow * IN2 + t * 32 + sc8, buf + 8192 + wid * 1024);
  };
  auto WRITEA = [&](char* buf) {
#pragma unroll
    for (int i = 0; i < 2; ++i) {
      uint4 o;
      o.x = f2bf(ra[i].x) | ((unsigned)f2bf(ra[i].y) << 16);
      o.y = f2bf(ra[i].z) | ((unsigned)f2bf(ra[i].w) << 16);
      o.z = f2bf(rb[i].x) | ((unsigned)f2bf(rb[i].y) << 16);
      o.w = f2bf(rb[i].z) | ((unsigned)f2bf(rb[i].w) << 16);
      *(uint4*)(buf + (wid * 2 + i) * 1024 + lane * 16) = o;
    }
  };
  auto COMPUTE = [&](const char* buf) {
    short8 af[4], bf[2];
#pragma unroll
    for (int m = 0; m < 4; ++m)
      af[m] = *(const short8*)(buf + (wrow + m * 16 + l16) * 64 + rdx);
#pragma unroll
    for (int n = 0; n < 2; ++n)
      bf[n] = *(const short8*)(buf + 8192 + (wcol + n * 16 + l16) * 64 + rdx);
    __builtin_amdgcn_s_setprio(1);
#pragma unroll
    for (int m = 0; m < 4; ++m)
#pragma unroll
      for (int n = 0; n < 2; ++n)
        acc[m][n] = mfma16(af[m], bf[n], acc[m][n]);
    __builtin_amdgcn_s_setprio(0);
  };

  LOADA(0); GW(0, buf0); WRITEA(buf0);
  __syncthreads();
#pragma unroll 1
  for (int t = 0; t < 8; t += 2) {
    LOADA(t + 1); GW(t + 1, buf1);
    COMPUTE(buf0);
    WRITEA(buf1);
    __syncthreads();
    if (t + 2 < 8) { LOADA(t + 2); GW(t + 2, buf0); }
    COMPUTE(buf1);
    if (t + 2 < 8) WRITEA(buf0);
    __syncthreads();
  }

  const int rbase = (lane >> 4) * 4;
#pragma unroll
  for (int m = 0; m < 4; ++m)
#pragma unroll
    for (int n = 0; n < 2; ++n) {
      int col = col0 + wcol + n * 16 + l16;
      float bv = bias[col];
#pragma unroll
      for (int e = 0; e < 4; ++e) {
        int row = row0 + wrow + m * 16 + rbase + e;
        float v = acc[m][n][e] + bv;
        v = v > 0.f ? v : 0.f;
        X[(size_t)row * H2 + col] = f2bf(v);
      }
    }
}

// ---------------------------------------------------------------------------
// GRU: tile 128r x 64j, 4 waves 2x2 (64r x 32j), 6 W panels, merged r/z acc.
// BK=32 double-buffered 2-phase: STAGE(t+1) -> COMPUTE(t) -> barrier(drain).
// LDS/buf = X 8K + H 8K + W 24K = 40K; x2 = 80 KB.
// ---------------------------------------------------------------------------
__global__ __launch_bounds__(256, 2)
void gru_kernel(const ushort_t* __restrict__ X16,
                const ushort_t* __restrict__ H16,
                const ushort_t* __restrict__ Wih,
                const ushort_t* __restrict__ Whh,
                const float* __restrict__ b_ih,
                const float* __restrict__ b_hh,
                float* __restrict__ out_h,
                ushort_t* __restrict__ h16b) {
  __shared__ char ldsb[81920];
  const int tid  = threadIdx.x;
  const int lane = tid & 63, wid = tid >> 6;
  const int l16  = lane & 15;
  const int bid  = blockIdx.x;
  const int lin  = (bid & 7) * 512 + (bid >> 3);     // XCD-local work order
  const int row0 = (lin >> 3) * 128;
  const int j0   = (lin & 7) * 64;
  const int wrow = (wid >> 1) * 64;
  const int wcol = (wid & 1) * 32;
  const int lr   = lane >> 2;
  const int sc8  = ((lane & 3) ^ (lr & 3)) * 8;
  const int rdx  = (((lane >> 4) ^ (lane & 3)) << 4);

  f32x4 accR[4][2] = {}, accZ[4][2] = {}, accIN[4][2] = {}, accHN[4][2] = {};

  const int xc0 = wid * 2;
  const size_t xrow0 = (size_t)(row0 + xc0 * 16 + lr) * H2 + sc8;

  auto STAGE = [&](int t, char* buf) {
    const int k0 = t * 32;
#pragma unroll
    for (int i = 0; i < 2; ++i) {
      const int c = xc0 + i;
      gload16(X16 + xrow0 + (size_t)i * 16 * H2 + k0, buf + c * 1024);
      gload16(H16 + xrow0 + (size_t)i * 16 * H2 + k0, buf + 8192 + c * 1024);
    }
#pragma unroll
    for (int i = 0; i < 6; ++i) {
      const int g = wid * 6 + i;
      const int p = g >> 2;
      const int jrow = j0 + (g & 3) * 16 + lr;
      const ushort_t* src = (p < 3)
          ? Wih + (size_t)(p * H2 + jrow) * H2
          : Whh + (size_t)((p - 3) * H2 + jrow) * H2;
      gload16(src + k0 + sc8, buf + 16384 + g * 1024);
    }
  };

  auto COMPUTE = [&](const char* buf) {
    short8 ax[4], ah[4];
#pragma unroll
    for (int m = 0; m < 4; ++m) {
      const int off = (wrow + m * 16 + l16) * 64 + rdx;
      ax[m] = *(const short8*)(buf + off);
      ah[m] = *(const short8*)(buf + 8192 + off);
    }
    __builtin_amdgcn_s_setprio(1);
#pragma unroll
    for (int n = 0; n < 2; ++n) {
      const int woff = 16384 + (wcol + n * 16 + l16) * 64 + rdx;
      short8 b0 = *(const short8*)(buf + woff);
      short8 b1 = *(const short8*)(buf + woff + 4096);
      short8 b2 = *(const short8*)(buf + woff + 8192);
      short8 b3 = *(const short8*)(buf + woff + 12288);
      short8 b4 = *(const short8*)(buf + woff + 16384);
      short8 b5 = *(const short8*)(buf + woff + 20480);
#pragma unroll
      for (int m = 0; m < 4; ++m) accR[m][n] = mfma16(ax[m], b0, accR[m][n]);
#pragma unroll
      for (int m = 0; m < 4; ++m) accZ[m][n] = mfma16(ax[m], b1, accZ[m][n]);
#pragma unroll
      for (int m = 0; m < 4; ++m) accIN[m][n] = mfma16(ax[m], b2, accIN[m][n]);
#pragma unroll
      for (int m = 0; m < 4; ++m) accHN[m][n] = mfma16(ah[m], b5, accHN[m][n]);
#pragma unroll
      for (int m = 0; m < 4; ++m) accR[m][n] = mfma16(ah[m], b3, accR[m][n]);
#pragma unroll
      for (int m = 0; m < 4; ++m) accZ[m][n] = mfma16(ah[m], b4, accZ[m][n]);
    }
    __builtin_amdgcn_s_setprio(0);
  };

  char* buf0 = ldsb;
  char* buf1 = ldsb + 40960;
  STAGE(0, buf0);
  __syncthreads();
#pragma unroll 1
  for (int t = 0; t < 16; t += 2) {
    STAGE(t + 1, buf1);
    COMPUTE(buf0);
    __syncthreads();
    if (t + 2 < 16) STAGE(t + 2, buf0);
    COMPUTE(buf1);
    __syncthreads();
  }

  const int rbase = (lane >> 4) * 4;
#pragma unroll
  for (int n = 0; n < 2; ++n) {
    int j = j0 + wcol + n * 16 + l16;
    float brr = b_ih[j] + b_hh[j];
    float bzz = b_ih[H2 + j] + b_hh[H2 + j];
    float bin = b_ih[2 * H2 + j];
    float bhn = b_hh[2 * H2 + j];
#pragma unroll
    for (int m = 0; m < 4; ++m) {
#pragma unroll
      for (int e = 0; e < 4; ++e) {
        int row = row0 + wrow + m * 16 + rbase + e;
        float r  = sigm(accR[m][n][e] + brr);
        float z  = sigm(accZ[m][n][e] + bzz);
        float nn = tanh_fast(accIN[m][n][e] + bin + r * (accHN[m][n][e] + bhn));
        float hp = bf2f(H16[(size_t)row * H2 + j]);
        float h  = (1.f - z) * nn + z * hp;
        out_h[(size_t)row * H2 + j] = h;
        if (h16b) h16b[(size_t)row * H2 + j] = f2bf(h);
      }
    }
  }
}

// ---------------------------------------------------------------------------
// heads: q1/q2 interleaved.  128-row blocks (512 blocks = 1 full round),
// 4 waves x 32 rows, each wave all 64 cols.  W (both heads) staged to LDS
// once (64 KB, swizzled); A-fragments loaded directly global->VGPR.
// ---------------------------------------------------------------------------
__global__ __launch_bounds__(256, 2)
void heads_bf16_kernel(const ushort_t* __restrict__ Hsrc,
                       const ushort_t* __restrict__ Wq1,
                       const ushort_t* __restrict__ Wq2,
                       const float* __restrict__ b21,
                       const float* __restrict__ b22,
                       float* __restrict__ outq) {
  __shared__ char WL[65536];
  const int tid  = threadIdx.x;
  const int lane = tid & 63, wid = tid >> 6;
  const int l16  = lane & 15;
  const int row0 = blockIdx.x * 128;
  const int wrow = wid * 32;
  const int kq   = lane >> 4;

#pragma unroll
  for (int i = 0; i < 16; ++i) {                // W: 64 rows, 1 KB each
    const int g = wid * 16 + i;
    const ushort_t* src =
        (g < 32) ? Wq1 + (size_t)g * H2 : Wq2 + (size_t)(g - 32) * H2;
    gload16(src + ((lane ^ (g & 7)) * 8), WL + g * 1024);
  }
  __syncthreads();

  f32x4 acc[2][4] = {};
#pragma unroll 2
  for (int kc = 0; kc < 8; ++kc) {
    short8 a[2][2];
#pragma unroll
    for (int m = 0; m < 2; ++m) {
      const ushort_t* p =
          Hsrc + (size_t)(row0 + wrow + m * 16 + l16) * H2 + kc * 64 + kq * 8;
      a[0][m] = *(const short8*)p;
      a[1][m] = *(const short8*)(p + 32);
    }
#pragma unroll
    for (int kk = 0; kk < 2; ++kk) {
      const int ckb = kc * 8 + kk * 4 + kq;
#pragma unroll
      for (int n = 0; n < 4; ++n) {
        const int rr = n * 16 + l16;
        short8 b = *(const short8*)(WL + rr * 1024 + ((ckb ^ (rr & 7)) << 4));
#pragma unroll
        for (int m = 0; m < 2; ++m)
          acc[m][n] = mfma16(a[kk][m], b, acc[m][n]);
      }
    }
  }

  const int rbase = (lane >> 4) * 4;
#pragma unroll
  for (int n = 0; n < 4; ++n) {
    const int hd  = n >> 1;
    const int col = (n & 1) * 16 + l16;
    const float bv = hd ? b22[col] : b21[col];
#pragma unroll
    for (int m = 0; m < 2; ++m)
#pragma unroll
      for (int e = 0; e < 4; ++e) {
        const int row = row0 + wrow + m * 16 + rbase + e;
        outq[(size_t)(2 * row + hd) * NA + col] = acc[m][n][e] + bv;
      }
  }
}

// fallback: same structure, A read from fp32 h (cvt in registers)
__global__ __launch_bounds__(256, 2)
void heads_f32_kernel(const float* __restrict__ Hsrc,
                      const ushort_t* __restrict__ Wq1,
                      const ushort_t* __restrict__ Wq2,
                      const float* __restrict__ b21,
                      const float* __restrict__ b22,
                      float* __restrict__ outq) {
  __shared__ char WL[65536];
  const int tid  = threadIdx.x;
  const int lane = tid & 63, wid = tid >> 6;
  const int l16  = lane & 15;
  const int row0 = blockIdx.x * 128;
  const int wrow = wid * 32;
  const int kq   = lane >> 4;

#pragma unroll
  for (int i = 0; i < 16; ++i) {
    const int g = wid * 16 + i;
    const ushort_t* src =
        (g < 32) ? Wq1 + (size_t)g * H2 : Wq2 + (size_t)(g - 32) * H2;
    gload16(src + ((lane ^ (g & 7)) * 8), WL + g * 1024);
  }
  __syncthreads();

  f32x4 acc[2][4] = {};
#pragma unroll 2
  for (int kc = 0; kc < 8; ++kc) {
    short8 a[2][2];
#pragma unroll
    for (int m = 0; m < 2; ++m)
#pragma unroll
      for (int kk = 0; kk < 2; ++kk) {
        const float* p = Hsrc +
            (size_t)(row0 + wrow + m * 16 + l16) * H2 + kc * 64 + kk * 32 + kq * 8;
        float4 f0 = *(const float4*)p;
        float4 f1 = *(const float4*)(p + 4);
        uint4 o;
        o.x = f2bf(f0.x) | ((unsigned)f2bf(f0.y) << 16);
        o.y = f2bf(f0.z) | ((unsigned)f2bf(f0.w) << 16);
        o.z = f2bf(f1.x) | ((unsigned)f2bf(f1.y) << 16);
        o.w = f2bf(f1.z) | ((unsigned)f2bf(f1.w) << 16);
        a[kk][m] = __builtin_bit_cast(short8, o);
      }
#pragma unroll
    for (int kk = 0; kk < 2; ++kk) {
      const int ckb = kc * 8 + kk * 4 + kq;
#pragma unroll
      for (int n = 0; n < 4; ++n) {
        const int rr = n * 16 + l16;
        short8 b = *(const short8*)(WL + rr * 1024 + ((ckb ^ (rr & 7)) << 4));
#pragma unroll
        for (int m = 0; m < 2; ++m)
          acc[m][n] = mfma16(a[kk][m], b, acc[m][n]);
      }
    }
  }

  const int rbase = (lane >> 4) * 4;
#pragma unroll
  for (int n = 0; n < 4; ++n) {
    const int hd  = n >> 1;
    const int col = (n & 1) * 16 + l16;
    const float bv = hd ? b22[col] : b21[col];
#pragma unroll
    for (int m = 0; m < 2; ++m)
#pragma unroll
      for (int e = 0; e < 4; ++e) {
        const int row = row0 + wrow + m * 16 + rbase + e;
        outq[(size_t)(2 * row + hd) * NA + col] = acc[m][n][e] + bv;
      }
  }
}

// ---------------------------------------------------------------------------
extern "C" void kernel_launch(void* const* d_in, const int* in_sizes, int n_in,
                              void* d_out, int out_size, void* d_ws,
                              size_t ws_size, hipStream_t stream) {
  (void)in_sizes; (void)n_in; (void)out_size;
  const float* inputs = (const float*)d_in[0];
  const float* hidden = (const float*)d_in[1];
  const float* W1     = (const float*)d_in[2];
  const float* b1     = (const float*)d_in[3];
  const float* W_ih   = (const float*)d_in[4];
  const float* W_hh   = (const float*)d_in[5];
  const float* b_ih   = (const float*)d_in[6];
  const float* b_hh   = (const float*)d_in[7];
  const float* W21    = (const float*)d_in[8];
  const float* b21    = (const float*)d_in[9];
  const float* W22    = (const float*)d_in[10];
  const float* b22    = (const float*)d_in[11];
  float* out = (float*)d_out;

  char* ws = (char*)d_ws;
  size_t off = 0;
  ushort_t* h16   = (ushort_t*)(ws + off); off += (size_t)BATCH * H2 * 2;
  ushort_t* x16   = (ushort_t*)(ws + off); off += (size_t)BATCH * H2 * 2;
  ushort_t* W1_16 = (ushort_t*)(ws + off); off += (size_t)H2 * IN2 * 2;
  ushort_t* Wih16 = (ushort_t*)(ws + off); off += (size_t)3 * H2 * H2 * 2;
  ushort_t* Whh16 = (ushort_t*)(ws + off); off += (size_t)3 * H2 * H2 * 2;
  ushort_t* W2116 = (ushort_t*)(ws + off); off += (size_t)NA * H2 * 2;
  ushort_t* W2216 = (ushort_t*)(ws + off); off += (size_t)NA * H2 * 2;
  size_t base_need = off;
  ushort_t* h16b = nullptr;
  if (ws_size >= base_need + (size_t)BATCH * H2 * 2)
    h16b = (ushort_t*)(ws + base_need);

  cvt_all<<<8192, 256, 0, stream>>>(hidden, W1, W_ih, W_hh, W21, W22,
                                    h16, W1_16, Wih16, Whh16, W2116, W2216);

  fc1_kernel<<<4096, 256, 0, stream>>>(inputs, W1_16, b1, x16);

  float* out_h = out + QELEMS;
  gru_kernel<<<4096, 256, 0, stream>>>(
      x16, h16, Wih16, Whh16, b_ih, b_hh, out_h, h16b);

  if (h16b)
    heads_bf16_kernel<<<BATCH / 128, 256, 0, stream>>>(h16b, W2116, W2216,
                                                       b21, b22, out);
  else
    heads_f32_kernel<<<BATCH / 128, 256, 0, stream>>>(out_h, W2116, W2216,
                                                      b21, b22, out);
}